// Round 2
// baseline (331.365 us; speedup 1.0000x reference)
//
#include <hip/hip_runtime.h>

// Problem constants
#define B_ 2
#define N_ 196608
#define K_ 9
#define F_ 64

typedef __attribute__((ext_vector_type(8))) short short8;
typedef __attribute__((ext_vector_type(8))) unsigned short ushort8;
typedef __attribute__((ext_vector_type(4))) float f32x4;

__device__ __forceinline__ unsigned short f2bf(float f) {
  unsigned u = __builtin_bit_cast(unsigned, f);
  u = (u + 0x7fffu + ((u >> 16) & 1u)) >> 16;   // RNE
  return (unsigned short)u;
}

// x fp32 [B][N][64] -> bf16 bits, 16 elems/thread (64B read, 32B write per thread)
__global__ __launch_bounds__(256) void cvt_x_kernel(const float* __restrict__ x,
                                                    unsigned short* __restrict__ xb) {
  const long i = (long)blockIdx.x * 256 + threadIdx.x;  // one per 16 elements
  const float4* src = (const float4*)x + 4 * i;
  float4 v[4];
#pragma unroll
  for (int j = 0; j < 4; ++j) v[j] = src[j];
  ushort8 r0, r1;
  r0[0] = f2bf(v[0].x); r0[1] = f2bf(v[0].y); r0[2] = f2bf(v[0].z); r0[3] = f2bf(v[0].w);
  r0[4] = f2bf(v[1].x); r0[5] = f2bf(v[1].y); r0[6] = f2bf(v[1].z); r0[7] = f2bf(v[1].w);
  r1[0] = f2bf(v[2].x); r1[1] = f2bf(v[2].y); r1[2] = f2bf(v[2].z); r1[3] = f2bf(v[2].w);
  r1[4] = f2bf(v[3].x); r1[5] = f2bf(v[3].y); r1[6] = f2bf(v[3].z); r1[7] = f2bf(v[3].w);
  ((ushort8*)xb)[2 * i] = r0;
  ((ushort8*)xb)[2 * i + 1] = r1;
}

// W fp32 [9][64][64] (k,f,o) -> Wt bf16 [9][64][64] (k,o,f)
__global__ __launch_bounds__(256) void cvt_w_kernel(const float* __restrict__ W,
                                                    unsigned short* __restrict__ wt) {
  const int i = blockIdx.x * 256 + threadIdx.x;  // i = k*4096 + o*64 + f
  const int k = i >> 12;
  const int rem = i & 4095;
  const int o = rem >> 6;
  const int f = rem & 63;
  wt[i] = f2bf(W[(k << 12) + (f << 6) + o]);
}

// Main: block = 256 thr (4 waves); tile = 128 rows x 64 cols.
// Wave w: rows w*32 .. w*32+31 (2 subtiles of 16), all 64 cols (4 col-tiles).
// All 36 A-fragment gathers issued upfront (deep MLP); adjc staged via LDS.
__global__ __launch_bounds__(256, 2) void nhconv_main(
    const short* __restrict__ xb,    // [B][N][64] bf16 bits
    const int* __restrict__ adjc,    // [N][9] int32
    const short* __restrict__ wt,    // [9][64][64] bf16 bits, Wt[k][o][f]
    const float* __restrict__ bias,  // [64]
    float* __restrict__ out) {       // [B][N][64] fp32
  __shared__ int s_adj[128 * K_];

  const int bb = blockIdx.y;
  const int n0 = blockIdx.x * 128;
  const int tid = (int)threadIdx.x;

  // Cooperative coalesced load of this tile's adjacency (1152 ints)
#pragma unroll
  for (int i = tid; i < 128 * K_; i += 256) s_adj[i] = adjc[n0 * K_ + i];
  __syncthreads();

  const int w = tid >> 6;          // wave 0..3
  const int l = tid & 63;          // lane
  const int q = l >> 4;            // quad 0..3
  const int c = l & 15;

  const int r0 = w * 32 + c;       // subtile-0 row (A row m = lane&15)
  const int r1 = r0 + 16;          // subtile-1 row
  const short* xB = xb + (size_t)bb * ((size_t)N_ * F_);
  const int foq = q * 8;           // lane's k-chunk offset within a 32-elem half

  // ---- Issue ALL 36 gather loads upfront (fills the memory pipe) ----
  short8 A0[K_][2], A1[K_][2];
#pragma unroll
  for (int k = 0; k < K_; ++k) {
    const short* p0 = xB + ((size_t)s_adj[r0 * K_ + k] << 6) + foq;
    A0[k][0] = *(const short8*)p0;
    A0[k][1] = *(const short8*)(p0 + 32);
  }
#pragma unroll
  for (int k = 0; k < K_; ++k) {
    const short* p1 = xB + ((size_t)s_adj[r1 * K_ + k] << 6) + foq;
    A1[k][0] = *(const short8*)p1;
    A1[k][1] = *(const short8*)(p1 + 32);
  }

  f32x4 acc[2][4];
#pragma unroll
  for (int s = 0; s < 2; ++s)
#pragma unroll
    for (int ct = 0; ct < 4; ++ct)
      acc[s][ct] = (f32x4){0.f, 0.f, 0.f, 0.f};

  // ---- MFMA loop: B-frags from global (L1-hot, 73.7 KB total) ----
#pragma unroll
  for (int k = 0; k < K_; ++k) {
#pragma unroll
    for (int fs = 0; fs < 2; ++fs) {
      const short* wk = wt + (k << 12) + fs * 32 + foq + (c << 6);  // + ct*1024
#pragma unroll
      for (int ct = 0; ct < 4; ++ct) {
        const short8 bf = *(const short8*)(wk + (ct << 10));
        acc[0][ct] = __builtin_amdgcn_mfma_f32_16x16x32_bf16(A0[k][fs], bf, acc[0][ct], 0, 0, 0);
        acc[1][ct] = __builtin_amdgcn_mfma_f32_16x16x32_bf16(A1[k][fs], bf, acc[1][ct], 0, 0, 0);
      }
    }
  }

  // Epilogue: C col = lane&15, row = quad*4 + reg
  float bv[4];
#pragma unroll
  for (int ct = 0; ct < 4; ++ct) bv[ct] = bias[ct * 16 + c];

  const size_t outbase = ((size_t)bb * N_ + (size_t)(n0 + w * 32)) * F_;
#pragma unroll
  for (int s = 0; s < 2; ++s) {
#pragma unroll
    for (int ct = 0; ct < 4; ++ct) {
#pragma unroll
      for (int r = 0; r < 4; ++r) {
        const int row = s * 16 + q * 4 + r;
        out[outbase + (size_t)row * F_ + ct * 16 + c] = acc[s][ct][r] + bv[ct];
      }
    }
  }
}

extern "C" void kernel_launch(void* const* d_in, const int* in_sizes, int n_in,
                              void* d_out, int out_size, void* d_ws, size_t ws_size,
                              hipStream_t stream) {
  const float* x = (const float*)d_in[0];
  const int* adjc = (const int*)d_in[1];
  const float* W = (const float*)d_in[2];
  const float* bias = (const float*)d_in[3];
  float* out = (float*)d_out;

  unsigned short* xb = (unsigned short*)d_ws;                    // 50,331,648 B
  unsigned short* wt = (unsigned short*)((char*)d_ws + (size_t)B_ * N_ * F_ * 2);

  // x convert: 25,165,824 elems / 16 per thread / 256 per block = 6144 blocks
  cvt_x_kernel<<<6144, 256, 0, stream>>>(x, xb);
  // W convert+transpose: 36864 elems / 256 = 144 blocks
  cvt_w_kernel<<<144, 256, 0, stream>>>(W, wt);

  dim3 grid(N_ / 128, B_);
  nhconv_main<<<grid, 256, 0, stream>>>((const short*)xb, adjc, (const short*)wt,
                                        bias, out);
}